// Round 1
// baseline (2123.414 us; speedup 1.0000x reference)
//
#include <hip/hip_runtime.h>

#define OUT_L 4096
#define KL 9
#define PAD 4
#define CHUNK 505   // first 7 chunk lengths; last chunk = 561
#define WSTR (8 * KL)  // weight stride per i (8 chunks * 9 taps)

__device__ __forceinline__ int chunk_of(int l) {
    int c = l / CHUNK;
    return c > 7 ? 7 : c;
}

// x:    (64 bdk, 64 i, 4096 l)          fp32
// w:    (8 dk, 64 o, 64 i, 8 c, 9 f)    fp32
// bias: (8 dk, 64 o, 8 c)               fp32
// out:  (64 bdk, 64 o, 4096 l)          fp32
__global__ __launch_bounds__(256) void PartiallyUnsharedConv1d_kernel(
    const float* __restrict__ x,
    const float* __restrict__ w,
    const float* __restrict__ bias,
    float* __restrict__ out)
{
    int g   = blockIdx.x * blockDim.x + threadIdx.x;
    int lid = g & 511;           // 512 groups of 8 l's
    int o   = (g >> 9) & 63;
    int bdk = g >> 15;           // 0..63  = (b*2+d)*4+k
    int dk  = bdk & 7;           // (d*4+k)
    int l0  = lid << 3;

    int cA = chunk_of(l0);
    int cB = chunk_of(l0 + 7);

    const float* xrow  = x + (size_t)(bdk * 64) * OUT_L;
    const float* wbase = w + (size_t)((dk * 64 + o) * 64) * WSTR;

    float acc[8];

    if (cA == cB && l0 >= PAD && l0 + 11 < OUT_L) {
        // interior, chunk-uniform fast path
        float b0 = bias[(dk * 64 + o) * 8 + cA];
        #pragma unroll
        for (int j = 0; j < 8; ++j) acc[j] = b0;

        const float* wc = wbase + cA * KL;
        #pragma unroll 1
        for (int i = 0; i < 64; ++i) {
            const float* xp = xrow + i * OUT_L + l0 - PAD;  // 16B aligned: l0-4 ≡ 0 mod 4
            float4 v0 = *(const float4*)(xp);
            float4 v1 = *(const float4*)(xp + 4);
            float4 v2 = *(const float4*)(xp + 8);
            float4 v3 = *(const float4*)(xp + 12);
            float xv[16] = {v0.x, v0.y, v0.z, v0.w,
                            v1.x, v1.y, v1.z, v1.w,
                            v2.x, v2.y, v2.z, v2.w,
                            v3.x, v3.y, v3.z, v3.w};
            const float* wp = wc + i * WSTR;
            float wv[KL];
            #pragma unroll
            for (int f = 0; f < KL; ++f) wv[f] = wp[f];
            #pragma unroll
            for (int j = 0; j < 8; ++j) {
                #pragma unroll
                for (int f = 0; f < KL; ++f)
                    acc[j] = fmaf(wv[f], xv[j + f], acc[j]);
            }
        }
    } else {
        // chunk-boundary / array-edge path (rare)
        #pragma unroll
        for (int j = 0; j < 8; ++j)
            acc[j] = bias[(dk * 64 + o) * 8 + chunk_of(l0 + j)];

        #pragma unroll 1
        for (int i = 0; i < 64; ++i) {
            const float* xp = xrow + i * OUT_L;
            float xv[16];
            #pragma unroll
            for (int t = 0; t < 16; ++t) {
                int pos = l0 - PAD + t;
                xv[t] = (pos >= 0 && pos < OUT_L) ? xp[pos] : 0.0f;
            }
            const float* wi = wbase + i * WSTR;
            #pragma unroll
            for (int j = 0; j < 8; ++j) {
                const float* wp = wi + chunk_of(l0 + j) * KL;
                #pragma unroll
                for (int f = 0; f < KL; ++f)
                    acc[j] = fmaf(wp[f], xv[j + f], acc[j]);
            }
        }
    }

    float4* op = (float4*)(out + ((size_t)(bdk * 64 + o)) * OUT_L + l0);
    op[0] = make_float4(acc[0], acc[1], acc[2], acc[3]);
    op[1] = make_float4(acc[4], acc[5], acc[6], acc[7]);
}

extern "C" void kernel_launch(void* const* d_in, const int* in_sizes, int n_in,
                              void* d_out, int out_size, void* d_ws, size_t ws_size,
                              hipStream_t stream) {
    const float* x    = (const float*)d_in[0];
    const float* w    = (const float*)d_in[1];
    const float* bias = (const float*)d_in[2];
    float* out        = (float*)d_out;

    // total threads: 64 bdk * 64 o * 512 l-groups = 2,097,152 -> 8192 blocks of 256
    dim3 grid(8192), block(256);
    hipLaunchKernelGGL(PartiallyUnsharedConv1d_kernel, grid, block, 0, stream,
                       x, w, bias, out);
}

// Round 2
// 95.818 us; speedup vs baseline: 22.1610x; 22.1610x over previous
//
#include <hip/hip_runtime.h>

typedef __attribute__((ext_vector_type(8))) short bf16x8;
typedef __attribute__((ext_vector_type(4))) float f32x4;

#define IPAD 72            // padded i-dim: 64 + 8 bf16 (16B) bank-skew pad
#define XROWS 264          // 256 output l's + 8 halo
#define WSLICE (64 * IPAD) // 4608 bf16 per (dk,c,f) slice

static __device__ __forceinline__ ushort f2bf(float f) {
    union { float f; unsigned u; } v; v.f = f;
    unsigned r = v.u + 0x7FFF + ((v.u >> 16) & 1);   // RNE
    return (ushort)(r >> 16);
}

// w: (8 dk, 64 o, 64 i, 8 c, 9 f) fp32  ->  wt: (8 dk, 8 c, 9 f, 64 o, 72 i) bf16
__global__ __launch_bounds__(256) void wprep_kernel(const float* __restrict__ w,
                                                    ushort* __restrict__ wt) {
    __shared__ float raw[4608];
    int bid = blockIdx.x;          // dk*64 + o
    int dk = bid >> 6, o = bid & 63;
    const float* src = w + (size_t)bid * 4608;
    int t = threadIdx.x;
    #pragma unroll
    for (int j = 0; j < 18; ++j) raw[t + 256 * j] = src[t + 256 * j];
    __syncthreads();
    for (int p = 0; p < 18; ++p) {
        int idx = t + 256 * p;           // (cf, i): cf = idx>>6, i = idx&63
        int cf = idx >> 6, i = idx & 63;
        int c = cf / 9, f = cf - c * 9;
        wt[(size_t)(((dk * 8 + c) * 9 + f) * 64 + o) * IPAD + i] = f2bf(raw[i * 72 + c * 9 + f]);
    }
}

// x: (64 bdk, 64 i, 4096 l) fp32 ; bias: (8 dk, 64 o, 8 c) ; out: (64 bdk, 64 o, 4096 l)
__global__ __launch_bounds__(256) void conv_mfma_kernel(
    const float* __restrict__ x, const ushort* __restrict__ wt,
    const float* __restrict__ bias, float* __restrict__ out)
{
    __shared__ __align__(16) ushort XL[XROWS * IPAD];   // 38016 B, [l][i] transposed
    __shared__ __align__(16) ushort WL[2 * WSLICE];     // 18432 B, double-buffered [o][i]

    int bid = blockIdx.x;
    int b    = bid / 136;            // stride-136 => b-sharers of one W slice on same XCD
    int rem  = bid - b * 136;
    int dk   = rem / 17;
    int tile = rem - dk * 17;
    int c, lt;
    if (tile < 14) { c = tile >> 1; lt = tile & 1; } else { c = 7; lt = tile - 14; }
    int Sc = 505 * c;
    int Lc = (c == 7) ? 561 : 505;
    int lb = lt << 8;
    int V  = Lc - lb; if (V > 256) V = 256;

    int bdk = b * 8 + dk;
    int t = threadIdx.x;
    int lane = t & 63, wv = t >> 6;
    int ln16 = lane & 15, g = lane >> 4;
    int Lw = wv << 6;

    // ---- stage X (transpose + fp32->bf16): rows r -> global l = Sc+lb-4+r ----
    {
        const float* xb = x + (size_t)bdk * 64 * 4096;
        int rl  = t & 63;
        int i4q = t >> 6;            // 0..3
        for (int rb = 0; rb < 5; ++rb) {
            int r = rb * 64 + rl;
            if (r < XROWS) {
                int lg = Sc + lb - 4 + r;
                bool ok = (lg >= 0) && (lg < 4096);
                #pragma unroll
                for (int ib = 0; ib < 4; ++ib) {
                    int i0 = (i4q * 4 + ib) * 4;   // 0,4,...,60
                    ushort h0, h1, h2, h3;
                    h0 = f2bf(ok ? xb[(size_t)(i0 + 0) * 4096 + lg] : 0.0f);
                    h1 = f2bf(ok ? xb[(size_t)(i0 + 1) * 4096 + lg] : 0.0f);
                    h2 = f2bf(ok ? xb[(size_t)(i0 + 2) * 4096 + lg] : 0.0f);
                    h3 = f2bf(ok ? xb[(size_t)(i0 + 3) * 4096 + lg] : 0.0f);
                    uint2 pk;
                    pk.x = (unsigned)h0 | ((unsigned)h1 << 16);
                    pk.y = (unsigned)h2 | ((unsigned)h3 << 16);
                    *(uint2*)&XL[r * IPAD + i0] = pk;
                }
            }
        }
    }

    // ---- stage W tap f=0 into buf 0 ----
    const uint4* wcu = (const uint4*)wt + (size_t)(dk * 8 + c) * 9 * 576;  // 576 uint4 per f-slice
    {
        uint4 s0 = wcu[t];
        uint4 s1 = wcu[t + 256];
        uint4 s2; if (t < 64) s2 = wcu[t + 512];
        *(uint4*)&WL[(size_t)t * 8]         = s0;
        *(uint4*)&WL[(size_t)(t + 256) * 8] = s1;
        if (t < 64) *(uint4*)&WL[(size_t)(t + 512) * 8] = s2;
    }
    __syncthreads();

    f32x4 acc[4][4];
    #pragma unroll
    for (int a0 = 0; a0 < 4; ++a0)
        #pragma unroll
        for (int a1 = 0; a1 < 4; ++a1) acc[a0][a1] = (f32x4){0.f, 0.f, 0.f, 0.f};

    #pragma unroll 1
    for (int f = 0; f < 9; ++f) {
        int buf = f & 1;
        // T14: issue next tap's global loads before compute
        uint4 st0, st1, st2;
        if (f < 8) {
            const uint4* ws_ = wcu + (size_t)(f + 1) * 576;
            st0 = ws_[t];
            st1 = ws_[t + 256];
            if (t < 64) st2 = ws_[t + 512];
        }
        #pragma unroll
        for (int s = 0; s < 2; ++s) {
            bf16x8 av[4], bv[4];
            #pragma unroll
            for (int q = 0; q < 4; ++q) {
                av[q] = *(const bf16x8*)&XL[(Lw + q * 16 + ln16 + f) * IPAD + s * 32 + g * 8];
                bv[q] = *(const bf16x8*)&WL[buf * WSLICE + (q * 16 + ln16) * IPAD + s * 32 + g * 8];
            }
            #pragma unroll
            for (int mf = 0; mf < 4; ++mf)
                #pragma unroll
                for (int nf = 0; nf < 4; ++nf)
                    acc[mf][nf] = __builtin_amdgcn_mfma_f32_16x16x32_bf16(av[mf], bv[nf], acc[mf][nf], 0, 0, 0);
        }
        if (f < 8) {
            int ob = (buf ^ 1) * WSLICE;
            *(uint4*)&WL[ob + (size_t)t * 8]         = st0;
            *(uint4*)&WL[ob + (size_t)(t + 256) * 8] = st1;
            if (t < 64) *(uint4*)&WL[ob + (size_t)(t + 512) * 8] = st2;
            __syncthreads();
        }
    }

    // ---- epilogue: bias + masked store ----
    float* ob = out + (size_t)bdk * 64 * 4096;
    #pragma unroll
    for (int nf = 0; nf < 4; ++nf) {
        int o = nf * 16 + ln16;
        float bvs = bias[(dk * 64 + o) * 8 + c];
        #pragma unroll
        for (int mf = 0; mf < 4; ++mf) {
            int l0 = Lw + mf * 16 + g * 4;
            #pragma unroll
            for (int r = 0; r < 4; ++r) {
                int ll = l0 + r;
                if (ll < V) ob[(size_t)o * 4096 + Sc + lb + ll] = acc[mf][nf][r] + bvs;
            }
        }
    }
}

extern "C" void kernel_launch(void* const* d_in, const int* in_sizes, int n_in,
                              void* d_out, int out_size, void* d_ws, size_t ws_size,
                              hipStream_t stream) {
    const float* x    = (const float*)d_in[0];
    const float* wgt  = (const float*)d_in[1];
    const float* bias = (const float*)d_in[2];
    float* out        = (float*)d_out;
    ushort* wt        = (ushort*)d_ws;   // needs 8*8*9*64*72*2 = 5,308,416 B

    hipLaunchKernelGGL(wprep_kernel, dim3(512), dim3(256), 0, stream, wgt, wt);
    hipLaunchKernelGGL(conv_mfma_kernel, dim3(1088), dim3(256), 0, stream, x, wt, bias, out);
}

// Round 3
// 92.137 us; speedup vs baseline: 23.0463x; 1.0399x over previous
//
#include <hip/hip_runtime.h>

typedef __attribute__((ext_vector_type(8))) short bf16x8;
typedef __attribute__((ext_vector_type(4))) float f32x4;

#define IPAD 72            // padded i-dim for W slices (16B-aligned rows)
#define WSLICE (64 * IPAD) // 4608 ushorts = 9216 B per (dk,c,f) slice
#define XT_ROWS 4104       // x_pad rows: 4 + 4096 + 4
#define XT_RB 128          // bytes per xT row (64 i * 2B)
#define XT_STRIDE ((size_t)XT_ROWS * XT_RB)      // 525312 B per bdk
#define WT_BYTES (8ull * 8 * 9 * 64 * IPAD * 2)  // 5,308,416
#define XT_BYTES (64ull * XT_STRIDE)             // 33,619,968

#define AS1C(p) ((const __attribute__((address_space(1))) void*)(p))
#define AS3(p)  ((__attribute__((address_space(3))) void*)(p))

static __device__ __forceinline__ ushort f2bf(float f) {
    union { float f; unsigned u; } v; v.f = f;
    unsigned r = v.u + 0x7FFF + ((v.u >> 16) & 1);   // RNE
    return (ushort)(r >> 16);
}

// w: (8 dk, 64 o, 64 i, 8 c, 9 f) fp32  ->  wt: (8 dk, 8 c, 9 f, 64 o, 72 i) bf16
__global__ __launch_bounds__(256) void wprep_kernel(const float* __restrict__ w,
                                                    ushort* __restrict__ wt) {
    __shared__ float raw[4608];
    int bid = blockIdx.x;          // dk*64 + o
    int dk = bid >> 6, o = bid & 63;
    const float* src = w + (size_t)bid * 4608;
    int t = threadIdx.x;
    #pragma unroll
    for (int j = 0; j < 18; ++j) raw[t + 256 * j] = src[t + 256 * j];
    __syncthreads();
    for (int p = 0; p < 18; ++p) {
        int idx = t + 256 * p;           // (cf, i)
        int cf = idx >> 6, i = idx & 63;
        int c = cf / 9, f = cf - c * 9;
        wt[(size_t)(((dk * 8 + c) * 9 + f) * 64 + o) * IPAD + i] = f2bf(raw[i * 72 + c * 9 + f]);
    }
}

// x: (64 bdk, 64 i, 4096 l) fp32 -> xT: (64 bdk, 4104 row, 64 i) bf16, chunk-swizzled
// element (row, i) stored at byte row*128 + ((i>>3)^(row&7))*16 + (i&7)*2
__global__ __launch_bounds__(256) void xprep_kernel(const float* __restrict__ x,
                                                    ushort* __restrict__ xT) {
    int bid = blockIdx.x;
    int bdk = bid >> 6;
    int lt  = bid & 63;            // 64-l tile
    int t = threadIdx.x;
    int q  = t >> 4;               // i-quad 0..15
    int lq = t & 15;               // l-quad within tile

    float4 v[4];
    #pragma unroll
    for (int k = 0; k < 4; ++k)
        v[k] = *(const float4*)(x + ((size_t)(bdk * 64) + q * 4 + k) * 4096 + lt * 64 + lq * 4);

    char* xrb = (char*)xT + (size_t)bdk * XT_STRIDE;
    #pragma unroll
    for (int m = 0; m < 4; ++m) {
        int row = lt * 64 + lq * 4 + m + 4;   // x_pad index
        int sw = row & 7;
        float a0 = ((const float*)&v[0])[m];
        float a1 = ((const float*)&v[1])[m];
        float a2 = ((const float*)&v[2])[m];
        float a3 = ((const float*)&v[3])[m];
        uint2 pk;
        pk.x = (unsigned)f2bf(a0) | ((unsigned)f2bf(a1) << 16);
        pk.y = (unsigned)f2bf(a2) | ((unsigned)f2bf(a3) << 16);
        int cby = (((q >> 1) ^ sw) * 16) + ((q & 1) * 8);
        *(uint2*)(xrb + (size_t)row * 128 + cby) = pk;
    }
    // zero pad rows
    if (lt == 0 && t < 64) {
        int row = t >> 4, qq = t & 15;
        int cby = (((qq >> 1) ^ (row & 7)) * 16) + ((qq & 1) * 8);
        uint2 z; z.x = 0u; z.y = 0u;
        *(uint2*)(xrb + (size_t)row * 128 + cby) = z;
    }
    if (lt == 63 && t < 64) {
        int row = 4100 + (t >> 4), qq = t & 15;
        int cby = (((qq >> 1) ^ (row & 7)) * 16) + ((qq & 1) * 8);
        uint2 z; z.x = 0u; z.y = 0u;
        *(uint2*)(xrb + (size_t)row * 128 + cby) = z;
    }
}

__global__ __launch_bounds__(256) void conv_mfma_kernel(
    const ushort* __restrict__ xT, const ushort* __restrict__ wt,
    const float* __restrict__ bias, float* __restrict__ out)
{
    __shared__ __align__(16) ushort XL[264 * 64];       // 33792 B, linear (swizzle in xT)
    __shared__ __align__(16) ushort WL[2 * WSLICE];     // 18432 B double-buffered

    int bid = blockIdx.x;
    int b    = bid / 136;
    int rem  = bid - b * 136;
    int dk   = rem / 17;
    int tile = rem - dk * 17;
    int c, lt;
    if (tile < 14) { c = tile >> 1; lt = tile & 1; } else { c = 7; lt = tile - 14; }
    int Sc = 505 * c;
    int lb = lt << 8;
    int V  = ((c == 7) ? 561 : 505) - lb; if (V > 256) V = 256;
    int bdk = b * 8 + dk;
    int R0  = Sc + lb;             // x_pad row of local row 0

    int t = threadIdx.x;
    int lane = t & 63, wv = t >> 6;
    int ln16 = lane & 15, g = lane >> 4;
    int Lw = wv << 6;

    // ---- async stage XL: 33 KB as 33 wave-chunks of 1 KB ----
    const char* xb = (const char*)xT + (size_t)bdk * XT_STRIDE;
    {
        int cb = wv * 1024 + lane * 16;
        #pragma unroll
        for (int it = 0; it < 8; ++it) {
            int B = it * 4096 + cb;
            int absr = R0 + (B >> 7);
            if (absr > 4103) absr = 4103;            // clamped rows are zero rows
            const char* ga = xb + (size_t)absr * 128 + (B & 127);
            __builtin_amdgcn_global_load_lds(AS1C(ga), AS3((char*)XL + it * 4096 + wv * 1024), 16, 0, 0);
        }
        if (wv == 0) {
            int B = 32768 + lane * 16;
            int absr = R0 + (B >> 7);
            if (absr > 4103) absr = 4103;
            const char* ga = xb + (size_t)absr * 128 + (B & 127);
            __builtin_amdgcn_global_load_lds(AS1C(ga), AS3((char*)XL + 32768), 16, 0, 0);
        }
    }

    // ---- async stage W (per-tap 9216 B), double-buffered ----
    const char* wcb = (const char*)wt + (size_t)(dk * 8 + c) * 9 * 9216;
    auto stageW = [&](int f, int buf) {
        const char* ws = wcb + (size_t)f * 9216;
        char* ldsb = (char*)WL + buf * 9216;
        __builtin_amdgcn_global_load_lds(AS1C(ws + wv * 1024 + lane * 16), AS3(ldsb + wv * 1024), 16, 0, 0);
        __builtin_amdgcn_global_load_lds(AS1C(ws + 4096 + wv * 1024 + lane * 16), AS3(ldsb + 4096 + wv * 1024), 16, 0, 0);
        if (wv == 0)
            __builtin_amdgcn_global_load_lds(AS1C(ws + 8192 + lane * 16), AS3(ldsb + 8192), 16, 0, 0);
    };
    stageW(0, 0);
    __syncthreads();   // vmcnt(0) drain: XL + W(0) resident

    f32x4 acc[4][4];
    #pragma unroll
    for (int a0 = 0; a0 < 4; ++a0)
        #pragma unroll
        for (int a1 = 0; a1 < 4; ++a1) acc[a0][a1] = (f32x4){0.f, 0.f, 0.f, 0.f};

    #pragma unroll 1
    for (int f = 0; f < 9; ++f) {
        int buf = f & 1;
        if (f < 8) stageW(f + 1, buf ^ 1);   // buf^1 readers finished before last barrier
        int swz = (R0 + Lw + ln16 + f) & 7;  // +16 per q doesn't change &7
        #pragma unroll
        for (int s = 0; s < 2; ++s) {
            bf16x8 av[4], bv[4];
            #pragma unroll
            for (int qq = 0; qq < 4; ++qq) {
                int r = Lw + qq * 16 + ln16 + f;
                av[qq] = *(const bf16x8*)((const char*)XL + r * 128 + (((s * 4 + g) ^ swz) * 16));
                bv[qq] = *(const bf16x8*)&WL[buf * WSLICE + (qq * 16 + ln16) * IPAD + s * 32 + g * 8];
            }
            #pragma unroll
            for (int mf = 0; mf < 4; ++mf)
                #pragma unroll
                for (int nf = 0; nf < 4; ++nf)
                    acc[mf][nf] = __builtin_amdgcn_mfma_f32_16x16x32_bf16(av[mf], bv[nf], acc[mf][nf], 0, 0, 0);
        }
        if (f < 8) __syncthreads();          // also drains next-tap W DMA (vmcnt 0 at barrier)
    }

    // ---- epilogue: bias + masked store ----
    float* ob = out + (size_t)bdk * 64 * 4096;
    #pragma unroll
    for (int nf = 0; nf < 4; ++nf) {
        int o = nf * 16 + ln16;
        float bvs = bias[(dk * 64 + o) * 8 + c];
        #pragma unroll
        for (int mf = 0; mf < 4; ++mf) {
            int l0 = Lw + mf * 16 + g * 4;
            #pragma unroll
            for (int r = 0; r < 4; ++r) {
                int ll = l0 + r;
                if (ll < V) ob[(size_t)o * 4096 + Sc + lb + ll] = acc[mf][nf][r] + bvs;
            }
        }
    }
}

// ---------------- fallback (round-2 proven path) if ws too small ----------------
__global__ __launch_bounds__(256) void conv_mfma_fb(
    const float* __restrict__ x, const ushort* __restrict__ wt,
    const float* __restrict__ bias, float* __restrict__ out)
{
    __shared__ __align__(16) ushort XL[264 * IPAD];
    __shared__ __align__(16) ushort WL[2 * WSLICE];
    int bid = blockIdx.x;
    int b = bid / 136, rem = bid - b * 136;
    int dk = rem / 17, tile = rem - dk * 17;
    int c, lt;
    if (tile < 14) { c = tile >> 1; lt = tile & 1; } else { c = 7; lt = tile - 14; }
    int Sc = 505 * c, lb = lt << 8;
    int V = ((c == 7) ? 561 : 505) - lb; if (V > 256) V = 256;
    int bdk = b * 8 + dk;
    int t = threadIdx.x, lane = t & 63, wv = t >> 6;
    int ln16 = lane & 15, g = lane >> 4, Lw = wv << 6;
    {
        const float* xb = x + (size_t)bdk * 64 * 4096;
        int rl = t & 63, i4q = t >> 6;
        for (int rb = 0; rb < 5; ++rb) {
            int r = rb * 64 + rl;
            if (r < 264) {
                int lg = Sc + lb - 4 + r;
                bool ok = (lg >= 0) && (lg < 4096);
                #pragma unroll
                for (int ib = 0; ib < 4; ++ib) {
                    int i0 = (i4q * 4 + ib) * 4;
                    ushort h0 = f2bf(ok ? xb[(size_t)(i0 + 0) * 4096 + lg] : 0.0f);
                    ushort h1 = f2bf(ok ? xb[(size_t)(i0 + 1) * 4096 + lg] : 0.0f);
                    ushort h2 = f2bf(ok ? xb[(size_t)(i0 + 2) * 4096 + lg] : 0.0f);
                    ushort h3 = f2bf(ok ? xb[(size_t)(i0 + 3) * 4096 + lg] : 0.0f);
                    uint2 pk;
                    pk.x = (unsigned)h0 | ((unsigned)h1 << 16);
                    pk.y = (unsigned)h2 | ((unsigned)h3 << 16);
                    *(uint2*)&XL[r * IPAD + i0] = pk;
                }
            }
        }
    }
    const uint4* wcu = (const uint4*)wt + (size_t)(dk * 8 + c) * 9 * 576;
    {
        uint4 s0 = wcu[t], s1 = wcu[t + 256]; uint4 s2; if (t < 64) s2 = wcu[t + 512];
        *(uint4*)&WL[(size_t)t * 8] = s0; *(uint4*)&WL[(size_t)(t + 256) * 8] = s1;
        if (t < 64) *(uint4*)&WL[(size_t)(t + 512) * 8] = s2;
    }
    __syncthreads();
    f32x4 acc[4][4];
    #pragma unroll
    for (int a0 = 0; a0 < 4; ++a0)
        #pragma unroll
        for (int a1 = 0; a1 < 4; ++a1) acc[a0][a1] = (f32x4){0.f, 0.f, 0.f, 0.f};
    #pragma unroll 1
    for (int f = 0; f < 9; ++f) {
        int buf = f & 1;
        uint4 st0, st1, st2;
        if (f < 8) {
            const uint4* ws_ = wcu + (size_t)(f + 1) * 576;
            st0 = ws_[t]; st1 = ws_[t + 256]; if (t < 64) st2 = ws_[t + 512];
        }
        #pragma unroll
        for (int s = 0; s < 2; ++s) {
            bf16x8 av[4], bv[4];
            #pragma unroll
            for (int q = 0; q < 4; ++q) {
                av[q] = *(const bf16x8*)&XL[(Lw + q * 16 + ln16 + f) * IPAD + s * 32 + g * 8];
                bv[q] = *(const bf16x8*)&WL[buf * WSLICE + (q * 16 + ln16) * IPAD + s * 32 + g * 8];
            }
            #pragma unroll
            for (int mf = 0; mf < 4; ++mf)
                #pragma unroll
                for (int nf = 0; nf < 4; ++nf)
                    acc[mf][nf] = __builtin_amdgcn_mfma_f32_16x16x32_bf16(av[mf], bv[nf], acc[mf][nf], 0, 0, 0);
        }
        if (f < 8) {
            int ob2 = (buf ^ 1) * WSLICE;
            *(uint4*)&WL[ob2 + (size_t)t * 8] = st0;
            *(uint4*)&WL[ob2 + (size_t)(t + 256) * 8] = st1;
            if (t < 64) *(uint4*)&WL[ob2 + (size_t)(t + 512) * 8] = st2;
            __syncthreads();
        }
    }
    float* ob = out + (size_t)bdk * 64 * 4096;
    #pragma unroll
    for (int nf = 0; nf < 4; ++nf) {
        int o = nf * 16 + ln16;
        float bvs = bias[(dk * 64 + o) * 8 + c];
        #pragma unroll
        for (int mf = 0; mf < 4; ++mf) {
            int l0 = Lw + mf * 16 + g * 4;
            #pragma unroll
            for (int r = 0; r < 4; ++r) {
                int ll = l0 + r;
                if (ll < V) ob[(size_t)o * 4096 + Sc + lb + ll] = acc[mf][nf][r] + bvs;
            }
        }
    }
}

extern "C" void kernel_launch(void* const* d_in, const int* in_sizes, int n_in,
                              void* d_out, int out_size, void* d_ws, size_t ws_size,
                              hipStream_t stream) {
    const float* x    = (const float*)d_in[0];
    const float* wgt  = (const float*)d_in[1];
    const float* bias = (const float*)d_in[2];
    float* out        = (float*)d_out;
    ushort* wt        = (ushort*)d_ws;

    hipLaunchKernelGGL(wprep_kernel, dim3(512), dim3(256), 0, stream, wgt, wt);
    if (ws_size >= WT_BYTES + XT_BYTES) {
        ushort* xT = (ushort*)((char*)d_ws + WT_BYTES);
        hipLaunchKernelGGL(xprep_kernel, dim3(4096), dim3(256), 0, stream, x, xT);
        hipLaunchKernelGGL(conv_mfma_kernel, dim3(1088), dim3(256), 0, stream, xT, wt, bias, out);
    } else {
        hipLaunchKernelGGL(conv_mfma_fb, dim3(1088), dim3(256), 0, stream, x, wt, bias, out);
    }
}

// Round 4
// 72.410 us; speedup vs baseline: 29.3248x; 1.2724x over previous
//
#include <hip/hip_runtime.h>

typedef __attribute__((ext_vector_type(8))) short bf16x8;
typedef __attribute__((ext_vector_type(4))) float f32x4;

#define XT_ROWS 4104                              // 4 pad + 4096 + 4 pad
#define XT_STRIDE ((size_t)XT_ROWS * 128)         // bytes per bdk
#define WT2_BYTES (8ull * 8 * 9 * 8192)           // 4,718,592
#define XT_BYTES (64ull * XT_STRIDE)              // 33,619,968

#define AS1C(p) ((const __attribute__((address_space(1))) void*)(p))
#define AS3(p)  ((__attribute__((address_space(3))) void*)(p))

static __device__ __forceinline__ ushort f2bf(float f) {
    union { float f; unsigned u; } v; v.f = f;
    unsigned r = v.u + 0x7FFF + ((v.u >> 16) & 1);   // RNE
    return (ushort)(r >> 16);
}

// w: (8 dk, 64 o, 64 i, 8 c, 9 f) fp32
// -> wt2: (8 dk, 8 c, 9 f) slices of 8192 B; element (o,i) at
//    o*128 + ((i>>3) ^ (o&7))*16 + (i&7)*2   (XOR-swizzle baked in)
__global__ __launch_bounds__(256) void wprep2_kernel(const float* __restrict__ w,
                                                     ushort* __restrict__ wt) {
    __shared__ float raw[4608];
    int bid = blockIdx.x;          // dk*64 + o
    int dk = bid >> 6, o = bid & 63;
    const float* src = w + (size_t)bid * 4608;
    int t = threadIdx.x;
    #pragma unroll
    for (int j = 0; j < 18; ++j) raw[t + 256 * j] = src[t + 256 * j];
    __syncthreads();
    int osw = o & 7;
    for (int p = 0; p < 18; ++p) {
        int idx = t + 256 * p;           // (cf, i)
        int cf = idx >> 6, i = idx & 63;
        int c = cf / 9, f = cf - c * 9;
        wt[(size_t)((dk * 8 + c) * 9 + f) * 4096 + o * 64 + ((i >> 3) ^ osw) * 8 + (i & 7)]
            = f2bf(raw[i * 72 + c * 9 + f]);
    }
}

// x: (64 bdk, 64 i, 4096 l) fp32 -> xT: (64 bdk, 4104 row, 128 B) bf16 swizzled:
// element (row,i) at row*128 + ((i>>3) ^ (row&7))*16 + (i&7)*2
__global__ __launch_bounds__(256) void xprep2_kernel(const float* __restrict__ x,
                                                     ushort* __restrict__ xT) {
    __shared__ ushort XB[128 * 72];     // [l][i], stride 72 ushorts (bank-skewed)
    int bid = blockIdx.x;
    int bdk = bid >> 5;
    int lt  = bid & 31;                 // 32 tiles x 128 l
    int t = threadIdx.x;
    int lq = t & 31, ig = t >> 5;       // ig 0..7 (8 i's each)
    int L0 = lt * 128;

    const float* xb = x + (size_t)bdk * 64 * 4096 + L0 + lq * 4;
    float4 v[8];
    #pragma unroll
    for (int j = 0; j < 8; ++j)
        v[j] = *(const float4*)(xb + (size_t)(ig * 8 + j) * 4096);

    #pragma unroll
    for (int k = 0; k < 4; ++k) {
        ushort h[8];
        #pragma unroll
        for (int j = 0; j < 8; ++j) h[j] = f2bf(((const float*)&v[j])[k]);
        uint4 pk;
        pk.x = (unsigned)h[0] | ((unsigned)h[1] << 16);
        pk.y = (unsigned)h[2] | ((unsigned)h[3] << 16);
        pk.z = (unsigned)h[4] | ((unsigned)h[5] << 16);
        pk.w = (unsigned)h[6] | ((unsigned)h[7] << 16);
        *(uint4*)&XB[(lq * 4 + k) * 72 + ig * 8] = pk;
    }
    __syncthreads();

    char* xrb = (char*)xT + (size_t)bdk * XT_STRIDE;
    #pragma unroll
    for (int it = 0; it < 4; ++it) {
        int idx = it * 256 + t;
        int r = idx >> 3, cc = idx & 7;
        uint4 vv = *(const uint4*)&XB[r * 72 + cc * 8];
        int rowB = L0 + r + 4;
        *(uint4*)(xrb + (size_t)rowB * 128 + ((cc ^ (rowB & 7)) * 16)) = vv;
    }
    // zero pad rows (0..3 and 4100..4103)
    if (lt == 0 && t < 32) {
        int r = t >> 3, cc = t & 7;
        uint4 z; z.x = z.y = z.z = z.w = 0u;
        *(uint4*)(xrb + (size_t)r * 128 + ((cc ^ (r & 7)) * 16)) = z;
    }
    if (lt == 31 && t < 32) {
        int r = 4100 + (t >> 3), cc = t & 7;
        uint4 z; z.x = z.y = z.z = z.w = 0u;
        *(uint4*)(xrb + (size_t)r * 128 + ((cc ^ (r & 7)) * 16)) = z;
    }
}

// conv: stage X(33.8KB) + all-W(73.7KB) once, counted-vmcnt tap pipeline.
__global__ __launch_bounds__(256, 1) void conv3_kernel(
    const ushort* __restrict__ xT, const ushort* __restrict__ wt,
    const float* __restrict__ bias, float* __restrict__ out)
{
    __shared__ __align__(16) char lds[107520];    // XL 33792 | WA 73728 ; epi reuses 66560
    ushort* XL = (ushort*)lds;
    const char* WAB = lds + 33792;
    float* OBF = (float*)lds;

    int bid = blockIdx.x;
    int b    = bid / 136;            // stride-136 => 8 b-sharers of one W slice on same XCD
    int rem  = bid - b * 136;
    int dk   = rem / 17;
    int tile = rem - dk * 17;
    int c, lt;
    if (tile < 14) { c = tile >> 1; lt = tile & 1; } else { c = 7; lt = tile - 14; }
    int Sc = 505 * c;
    int lb = lt << 8;
    int V  = ((c == 7) ? 561 : 505) - lb; if (V > 256) V = 256;
    int bdk = b * 8 + dk;
    int R0  = Sc + lb;               // x_pad row of local row 0

    int t = threadIdx.x;
    int lane = t & 63, wv = t >> 6;
    int ln16 = lane & 15, g = lane >> 4;
    int Lw = wv << 6;

    // ---- issue X stage (8 DMA/thread + 1 extra on wave0) ----
    const char* xb = (const char*)xT + (size_t)bdk * XT_STRIDE;
    #pragma unroll
    for (int it = 0; it < 8; ++it) {
        int B = it * 4096 + wv * 1024 + lane * 16;
        int absr = R0 + (B >> 7);
        if (absr > 4103) absr = 4103;            // clamped rows are zero rows
        __builtin_amdgcn_global_load_lds(AS1C(xb + (size_t)absr * 128 + (B & 127)),
                                         AS3(lds + it * 4096 + wv * 1024), 16, 0, 0);
    }
    if (wv == 0) {
        int B = 32768 + lane * 16;
        int absr = R0 + (B >> 7);
        if (absr > 4103) absr = 4103;
        __builtin_amdgcn_global_load_lds(AS1C(xb + (size_t)absr * 128 + (B & 127)),
                                         AS3(lds + 32768), 16, 0, 0);
    }

    // ---- issue ALL W taps, in tap order (2 DMA/thread/tap) ----
    const char* wcb = (const char*)wt + (size_t)(dk * 8 + c) * 9 * 8192;
    #pragma unroll
    for (int f = 0; f < 9; ++f) {
        __builtin_amdgcn_global_load_lds(AS1C(wcb + f * 8192 + wv * 2048 + lane * 16),
                                         AS3(lds + 33792 + f * 8192 + wv * 2048), 16, 0, 0);
        __builtin_amdgcn_global_load_lds(AS1C(wcb + f * 8192 + wv * 2048 + 1024 + lane * 16),
                                         AS3(lds + 33792 + f * 8192 + wv * 2048 + 1024), 16, 0, 0);
    }

    f32x4 acc[4][4];
    #pragma unroll
    for (int a0 = 0; a0 < 4; ++a0)
        #pragma unroll
        for (int a1 = 0; a1 < 4; ++a1) acc[a0][a1] = (f32x4){0.f, 0.f, 0.f, 0.f};

    auto tap = [&](int f) {
        int swz = (R0 + Lw + ln16 + f) & 7;      // +q*16 doesn't change &7
        #pragma unroll
        for (int s = 0; s < 2; ++s) {
            bf16x8 av[4], bv[4];
            #pragma unroll
            for (int q = 0; q < 4; ++q) {
                av[q] = *(const bf16x8*)((const char*)XL
                        + (size_t)(Lw + q * 16 + ln16 + f) * 128 + (((s * 4 + g) ^ swz) * 16));
                bv[q] = *(const bf16x8*)(WAB + (size_t)f * 8192
                        + (q * 16 + ln16) * 128 + (((s * 4 + g) ^ (ln16 & 7)) * 16));
            }
            #pragma unroll
            for (int mf = 0; mf < 4; ++mf)
                #pragma unroll
                for (int nf = 0; nf < 4; ++nf)
                    acc[mf][nf] = __builtin_amdgcn_mfma_f32_16x16x32_bf16(av[mf], bv[nf], acc[mf][nf], 0, 0, 0);
        }
    };

    // counted vmcnt: before tap f, my outstanding <= 2*(8-f)  =>  X + W0..Wf landed
#define TAPSTEP(N, F) \
    asm volatile("s_waitcnt vmcnt(" #N ")" ::: "memory"); \
    __builtin_amdgcn_s_barrier(); \
    __builtin_amdgcn_sched_barrier(0); \
    tap(F);

    TAPSTEP(16, 0) TAPSTEP(14, 1) TAPSTEP(12, 2) TAPSTEP(10, 3) TAPSTEP(8, 4)
    TAPSTEP(6, 5) TAPSTEP(4, 6) TAPSTEP(2, 7) TAPSTEP(0, 8)
#undef TAPSTEP

    // ---- epilogue: acc -> LDS [o][l] f32 (stride 260), then coalesced stores ----
    __syncthreads();
    #pragma unroll
    for (int nf = 0; nf < 4; ++nf) {
        int o = nf * 16 + ln16;
        float bvs = bias[(dk * 64 + o) * 8 + c];
        #pragma unroll
        for (int mf = 0; mf < 4; ++mf) {
            int l = Lw + mf * 16 + g * 4;
            f32x4 vv = acc[mf][nf];
            vv[0] += bvs; vv[1] += bvs; vv[2] += bvs; vv[3] += bvs;
            *(f32x4*)&OBF[o * 260 + l] = vv;
        }
    }
    __syncthreads();
    float* ob = out + (size_t)bdk * 64 * 4096 + Sc + lb;
    #pragma unroll
    for (int jj = 0; jj < 16; ++jj) {
        int o = wv + 4 * jj;
        #pragma unroll
        for (int k = 0; k < 4; ++k) {
            int l = lane + 64 * k;
            if (l < V) ob[(size_t)o * 4096 + l] = OBF[o * 260 + l];
        }
    }
}

extern "C" void kernel_launch(void* const* d_in, const int* in_sizes, int n_in,
                              void* d_out, int out_size, void* d_ws, size_t ws_size,
                              hipStream_t stream) {
    const float* x    = (const float*)d_in[0];
    const float* wgt  = (const float*)d_in[1];
    const float* bias = (const float*)d_in[2];
    float* out        = (float*)d_out;
    ushort* wt2       = (ushort*)d_ws;                       // 4,718,592 B
    ushort* xT        = (ushort*)((char*)d_ws + WT2_BYTES);  // 33,619,968 B

    hipLaunchKernelGGL(wprep2_kernel, dim3(512), dim3(256), 0, stream, wgt, wt2);
    hipLaunchKernelGGL(xprep2_kernel, dim3(2048), dim3(256), 0, stream, x, xT);
    hipLaunchKernelGGL(conv3_kernel, dim3(1088), dim3(256), 0, stream, xT, wt2, bias, out);
}

// Round 5
// 53.356 us; speedup vs baseline: 39.7969x; 1.3571x over previous
//
#include <hip/hip_runtime.h>

typedef __attribute__((ext_vector_type(8))) short bf16x8;
typedef __attribute__((ext_vector_type(4))) float f32x4;

#define WT2_BYTES (8ull * 8 * 9 * 8192)           // 4,718,592

static __device__ __forceinline__ ushort f2bf(float f) {
    union { float f; unsigned u; } v; v.f = f;
    unsigned r = v.u + 0x7FFF + ((v.u >> 16) & 1);   // RNE
    return (ushort)(r >> 16);
}
static __device__ __forceinline__ unsigned pk2(float a, float b) {
    return (unsigned)f2bf(a) | ((unsigned)f2bf(b) << 16);
}

// w: (8 dk, 64 o, 64 i, 8 c, 9 f) fp32
// -> wt2: (8 dk, 8 c, 9 f) slices of 8192 B; element (o,i) at byte
//    o*128 + ((i>>3) ^ (o&7))*16 + (i&7)*2   (XOR-swizzle baked in)
// block = (dk, o): coalesced reads, LDS-batched coalesced uint4 writes.
__global__ __launch_bounds__(256) void wprep3_kernel(const float* __restrict__ w,
                                                     ushort* __restrict__ wt) {
    __shared__ float raw[4608];          // [i][c*9+f]
    __shared__ ushort row[72 * 64];      // [c*9+f][swizzled 64 i]
    int bid = blockIdx.x;                // dk*64 + o
    int dk = bid >> 6, o = bid & 63;
    const float* src = w + (size_t)bid * 4608;
    int t = threadIdx.x;
    #pragma unroll
    for (int j = 0; j < 18; ++j) raw[t + 256 * j] = src[t + 256 * j];
    __syncthreads();
    int osw = o & 7;
    #pragma unroll
    for (int p = 0; p < 18; ++p) {
        int idx = t + 256 * p;           // (cf, i)
        int cf = idx >> 6, i = idx & 63;
        int c = cf / 9, f = cf - c * 9;
        row[cf * 64 + ((i >> 3) ^ osw) * 8 + (i & 7)] = f2bf(raw[i * 72 + c * 9 + f]);
    }
    __syncthreads();
    char* wb = (char*)wt + (size_t)dk * 8 * 9 * 8192 + o * 128;
    #pragma unroll
    for (int q = 0; q < 3; ++q) {
        int idx = q * 256 + t;           // (cf, cc)
        if (idx < 576) {
            int cf = idx >> 3, cc = idx & 7;
            *(uint4*)(wb + (size_t)cf * 8192 + cc * 16) = *(const uint4*)&row[cf * 64 + cc * 8];
        }
    }
}

// Fused conv: x fp32 -> in-kernel bf16 transpose to swizzled LDS; W direct to
// registers (no W LDS, no per-tap barriers); 3 blocks/CU.
__global__ __launch_bounds__(256, 3) void conv4_kernel(
    const float* __restrict__ x, const ushort* __restrict__ wt,
    const float* __restrict__ bias, float* __restrict__ out)
{
    __shared__ __align__(16) ushort XL[264 * 64];   // 33792 B, [r][i] swizzled

    int bid = blockIdx.x;
    int b = bid / 136, rem = bid - b * 136;       // b-sharers of W 136 apart (mod 8 == 0 -> same XCD)
    int dk = rem / 17, tile = rem - dk * 17;
    int c, lt;
    if (tile < 14) { c = tile >> 1; lt = tile & 1; } else { c = 7; lt = tile - 14; }
    int Sc = 505 * c, lb = lt << 8;
    int V = ((c == 7) ? 561 : 505) - lb; if (V > 256) V = 256;
    int bdk = b * 8 + dk;
    int R0 = Sc + lb;                             // padded row of local row 0

    int t = threadIdx.x, lane = t & 63, wv = t >> 6;
    int ln16 = lane & 15, g = lane >> 4, Lw = wv << 6;

    // per-lane W fragment bases (s=0 / s=1), swizzled layout
    const char* wsl = (const char*)wt + (size_t)(dk * 8 + c) * 9 * 8192 + ln16 * 128;
    const char* wlA = wsl + ((g ^ (ln16 & 7)) * 16);
    const char* wlB = wsl + (((4 + g) ^ (ln16 & 7)) * 16);

    bf16x8 w0[2][4], w1[2][4];
    auto loadW = [&](bf16x8 (&dst)[2][4], int f) {
        const char* bA = wlA + f * 8192;
        const char* bB = wlB + f * 8192;
        #pragma unroll
        for (int q = 0; q < 4; ++q) {
            dst[0][q] = *(const bf16x8*)(bA + q * 2048);
            dst[1][q] = *(const bf16x8*)(bB + q * 2048);
        }
    };

    loadW(w0, 0);   // in flight during X stage

    // ---- stage X: fp32 -> bf16 transpose into swizzled LDS ----
    {
        const float* xb = x + ((size_t)(bdk * 64 + wv * 16)) * 4096;  // wave's 16 i-rows
        bool edge = (R0 < 4) || (R0 > 3836);
        #pragma unroll
        for (int k = 0; k < 5; ++k) {
            int r = k * 64 + lane;                // local row (l-position)
            if (r < 264) {
                int xr = R0 + r - 4;              // x row index
                float v[16];
                if (!edge) {
                    #pragma unroll
                    for (int j = 0; j < 16; ++j) v[j] = xb[(size_t)j * 4096 + xr];
                } else {
                    bool ok = (xr >= 0) && (xr < 4096);
                    int xc = ok ? xr : 0;
                    #pragma unroll
                    for (int j = 0; j < 16; ++j) v[j] = ok ? xb[(size_t)j * 4096 + xc] : 0.0f;
                }
                uint4 A, B;
                A.x = pk2(v[0], v[1]);  A.y = pk2(v[2], v[3]);
                A.z = pk2(v[4], v[5]);  A.w = pk2(v[6], v[7]);
                B.x = pk2(v[8], v[9]);  B.y = pk2(v[10], v[11]);
                B.z = pk2(v[12], v[13]); B.w = pk2(v[14], v[15]);
                char* base = (char*)XL + r * 128;
                *(uint4*)(base + (((2 * wv)     ^ (r & 7)) * 16)) = A;
                *(uint4*)(base + (((2 * wv + 1) ^ (r & 7)) * 16)) = B;
            }
        }
    }
    loadW(w1, 1);
    __syncthreads();

    f32x4 acc[4][4];
    #pragma unroll
    for (int a0 = 0; a0 < 4; ++a0)
        #pragma unroll
        for (int a1 = 0; a1 < 4; ++a1) acc[a0][a1] = (f32x4){0.f, 0.f, 0.f, 0.f};

    auto tap = [&](bf16x8 (&wf)[2][4], int f) {
        int rbase = Lw + ln16 + f;
        int swz = rbase & 7;                      // +q*16 doesn't change &7
        #pragma unroll
        for (int s = 0; s < 2; ++s) {
            int cof = ((s * 4 + g) ^ swz) * 16;
            bf16x8 av[4];
            #pragma unroll
            for (int mf = 0; mf < 4; ++mf)
                av[mf] = *(const bf16x8*)((const char*)XL + (rbase + mf * 16) * 128 + cof);
            #pragma unroll
            for (int mf = 0; mf < 4; ++mf)
                #pragma unroll
                for (int nf = 0; nf < 4; ++nf)
                    acc[mf][nf] = __builtin_amdgcn_mfma_f32_16x16x32_bf16(av[mf], wf[s][nf], acc[mf][nf], 0, 0, 0);
        }
    };

    tap(w0, 0); loadW(w0, 2);
    tap(w1, 1); loadW(w1, 3);
    tap(w0, 2); loadW(w0, 4);
    tap(w1, 3); loadW(w1, 5);
    tap(w0, 4); loadW(w0, 6);
    tap(w1, 5); loadW(w1, 7);
    tap(w0, 6); loadW(w0, 8);
    tap(w1, 7);
    tap(w0, 8);

    // ---- epilogue: bias + direct f32x4 stores (4 lanes = 64 B contiguous) ----
    float* ob = out + ((size_t)(bdk * 64)) * 4096 + Sc + lb;
    #pragma unroll
    for (int nf = 0; nf < 4; ++nf) {
        int o = nf * 16 + ln16;
        float bvs = bias[(dk * 64 + o) * 8 + c];
        #pragma unroll
        for (int mf = 0; mf < 4; ++mf) {
            int l = Lw + mf * 16 + g * 4;
            f32x4 vv = acc[mf][nf];
            vv[0] += bvs; vv[1] += bvs; vv[2] += bvs; vv[3] += bvs;
            if (l + 4 <= V) {
                *(f32x4*)(ob + (size_t)o * 4096 + l) = vv;
            } else if (l < V) {
                #pragma unroll
                for (int r = 0; r < 4; ++r)
                    if (l + r < V) ob[(size_t)o * 4096 + l + r] = vv[r];
            }
        }
    }
}

extern "C" void kernel_launch(void* const* d_in, const int* in_sizes, int n_in,
                              void* d_out, int out_size, void* d_ws, size_t ws_size,
                              hipStream_t stream) {
    const float* x    = (const float*)d_in[0];
    const float* wgt  = (const float*)d_in[1];
    const float* bias = (const float*)d_in[2];
    float* out        = (float*)d_out;
    ushort* wt2       = (ushort*)d_ws;            // 4,718,592 B

    hipLaunchKernelGGL(wprep3_kernel, dim3(512), dim3(256), 0, stream, wgt, wt2);
    hipLaunchKernelGGL(conv4_kernel, dim3(1088), dim3(256), 0, stream, x, wt2, bias, out);
}

// Round 6
// 52.052 us; speedup vs baseline: 40.7941x; 1.0251x over previous
//
#include <hip/hip_runtime.h>

typedef __attribute__((ext_vector_type(8))) short bf16x8;
typedef __attribute__((ext_vector_type(4))) float f32x4;

#define WT2_BYTES (8ull * 8 * 9 * 8192)           // 4,718,592

static __device__ __forceinline__ ushort f2bf(float f) {
    union { float f; unsigned u; } v; v.f = f;
    unsigned r = v.u + 0x7FFF + ((v.u >> 16) & 1);   // RNE
    return (ushort)(r >> 16);
}
static __device__ __forceinline__ unsigned cvtpk(float a, float b) {
    unsigned r;
    asm("v_cvt_pk_bf16_f32 %0, %1, %2" : "=v"(r) : "v"(a), "v"(b));
    return r;   // lo = bf16(a), hi = bf16(b)
}

// w: (8 dk, 64 o, 64 i, 8 c, 9 f) fp32
// -> wt2: (8 dk, 8 c, 9 f) slices of 8192 B; element (o,i) at byte
//    o*128 + ((i>>3) ^ (o&7))*16 + (i&7)*2   (XOR-swizzle baked in)
__global__ __launch_bounds__(256) void wprep3_kernel(const float* __restrict__ w,
                                                     ushort* __restrict__ wt) {
    __shared__ float raw[4608];          // [i][c*9+f]
    __shared__ ushort row[72 * 64];      // [c*9+f][swizzled 64 i]
    int bid = blockIdx.x;                // dk*64 + o
    int dk = bid >> 6, o = bid & 63;
    const float* src = w + (size_t)bid * 4608;
    int t = threadIdx.x;
    #pragma unroll
    for (int j = 0; j < 18; ++j) raw[t + 256 * j] = src[t + 256 * j];
    __syncthreads();
    int osw = o & 7;
    #pragma unroll
    for (int p = 0; p < 18; ++p) {
        int idx = t + 256 * p;           // (cf, i)
        int cf = idx >> 6, i = idx & 63;
        int c = cf / 9, f = cf - c * 9;
        row[cf * 64 + ((i >> 3) ^ osw) * 8 + (i & 7)] = f2bf(raw[i * 72 + c * 9 + f]);
    }
    __syncthreads();
    char* wb = (char*)wt + (size_t)dk * 8 * 9 * 8192 + o * 128;
    #pragma unroll
    for (int q = 0; q < 3; ++q) {
        int idx = q * 256 + t;           // (cf, cc)
        if (idx < 576) {
            int cf = idx >> 3, cc = idx & 7;
            *(uint4*)(wb + (size_t)cf * 8192 + cc * 16) = *(const uint4*)&row[cf * 64 + cc * 8];
        }
    }
}

// Fused conv: x fp32 -> in-kernel bf16 transpose to swizzled LDS; W direct to
// registers (no W LDS, no per-tap barriers). launch_bounds(256,2): 256-reg
// budget so w0/w1/staging stay IN REGISTERS (the (256,3) cap spilled them).
__global__ __launch_bounds__(256, 2) void conv5_kernel(
    const float* __restrict__ x, const ushort* __restrict__ wt,
    const float* __restrict__ bias, float* __restrict__ out)
{
    __shared__ __align__(16) ushort XL[264 * 64];   // 33792 B, [r][i] swizzled

    int bid = blockIdx.x;
    int b = bid / 136, rem = bid - b * 136;       // b-sharers of W 136 apart (mod 8 == 0 -> same XCD)
    int dk = rem / 17, tile = rem - dk * 17;
    int c, lt;
    if (tile < 14) { c = tile >> 1; lt = tile & 1; } else { c = 7; lt = tile - 14; }
    int Sc = 505 * c, lb = lt << 8;
    int V = ((c == 7) ? 561 : 505) - lb; if (V > 256) V = 256;
    int bdk = b * 8 + dk;
    int R0 = Sc + lb;                             // padded row of local row 0

    int t = threadIdx.x, lane = t & 63, wv = t >> 6;
    int ln16 = lane & 15, g = lane >> 4, Lw = wv << 6;

    // per-lane W fragment bases (s=0 / s=1), swizzled layout
    const char* wsl = (const char*)wt + (size_t)(dk * 8 + c) * 9 * 8192 + ln16 * 128;
    const char* wlA = wsl + ((g ^ (ln16 & 7)) * 16);
    const char* wlB = wsl + (((4 + g) ^ (ln16 & 7)) * 16);

    bf16x8 w0[2][4], w1[2][4];
    auto loadW = [&](bf16x8 (&dst)[2][4], int f) {
        const char* bA = wlA + f * 8192;
        const char* bB = wlB + f * 8192;
        #pragma unroll
        for (int q = 0; q < 4; ++q) {
            dst[0][q] = *(const bf16x8*)(bA + q * 2048);
            dst[1][q] = *(const bf16x8*)(bB + q * 2048);
        }
    };

    loadW(w0, 0);   // in flight during X stage

    // ---- stage X: fp32 -> bf16 transpose into swizzled LDS ----
    {
        const float* xb = x + ((size_t)(bdk * 64 + wv * 16)) * 4096;  // wave's 16 i-rows
        bool edge = (R0 < 4) || (R0 > 3836);
        #pragma unroll
        for (int k = 0; k < 5; ++k) {
            int r = k * 64 + lane;                // local row (l-position)
            if (r < 264) {
                int xr = R0 + r - 4;              // x row index
                float v[16];
                if (!edge) {
                    #pragma unroll
                    for (int j = 0; j < 16; ++j) v[j] = xb[(size_t)j * 4096 + xr];
                } else {
                    bool ok = (xr >= 0) && (xr < 4096);
                    int xc = ok ? xr : 0;
                    #pragma unroll
                    for (int j = 0; j < 16; ++j) v[j] = ok ? xb[(size_t)j * 4096 + xc] : 0.0f;
                }
                uint4 A, B;
                A.x = cvtpk(v[0], v[1]);   A.y = cvtpk(v[2], v[3]);
                A.z = cvtpk(v[4], v[5]);   A.w = cvtpk(v[6], v[7]);
                B.x = cvtpk(v[8], v[9]);   B.y = cvtpk(v[10], v[11]);
                B.z = cvtpk(v[12], v[13]); B.w = cvtpk(v[14], v[15]);
                char* base = (char*)XL + r * 128;
                *(uint4*)(base + (((2 * wv)     ^ (r & 7)) * 16)) = A;
                *(uint4*)(base + (((2 * wv + 1) ^ (r & 7)) * 16)) = B;
            }
        }
    }
    loadW(w1, 1);
    __syncthreads();

    f32x4 acc[4][4];
    #pragma unroll
    for (int a0 = 0; a0 < 4; ++a0)
        #pragma unroll
        for (int a1 = 0; a1 < 4; ++a1) acc[a0][a1] = (f32x4){0.f, 0.f, 0.f, 0.f};

    auto tap = [&](bf16x8 (&wf)[2][4], int f) {
        int rbase = Lw + ln16 + f;
        int swz = rbase & 7;                      // +q*16 doesn't change &7
        #pragma unroll
        for (int s = 0; s < 2; ++s) {
            int cof = ((s * 4 + g) ^ swz) * 16;
            bf16x8 av[4];
            #pragma unroll
            for (int mf = 0; mf < 4; ++mf)
                av[mf] = *(const bf16x8*)((const char*)XL + (rbase + mf * 16) * 128 + cof);
            #pragma unroll
            for (int mf = 0; mf < 4; ++mf)
                #pragma unroll
                for (int nf = 0; nf < 4; ++nf)
                    acc[mf][nf] = __builtin_amdgcn_mfma_f32_16x16x32_bf16(av[mf], wf[s][nf], acc[mf][nf], 0, 0, 0);
        }
    };

    tap(w0, 0); loadW(w0, 2);
    tap(w1, 1); loadW(w1, 3);
    tap(w0, 2); loadW(w0, 4);
    tap(w1, 3); loadW(w1, 5);
    tap(w0, 4); loadW(w0, 6);
    tap(w1, 5); loadW(w1, 7);
    tap(w0, 6); loadW(w0, 8);
    tap(w1, 7);
    tap(w0, 8);

    // ---- epilogue: bias + direct f32x4 stores (4 lanes = 64 B contiguous) ----
    float* ob = out + ((size_t)(bdk * 64)) * 4096 + Sc + lb;
    #pragma unroll
    for (int nf = 0; nf < 4; ++nf) {
        int o = nf * 16 + ln16;
        float bvs = bias[(dk * 64 + o) * 8 + c];
        #pragma unroll
        for (int mf = 0; mf < 4; ++mf) {
            int l = Lw + mf * 16 + g * 4;
            f32x4 vv = acc[mf][nf];
            vv[0] += bvs; vv[1] += bvs; vv[2] += bvs; vv[3] += bvs;
            if (l + 4 <= V) {
                *(f32x4*)(ob + (size_t)o * 4096 + l) = vv;
            } else if (l < V) {
                #pragma unroll
                for (int r = 0; r < 4; ++r)
                    if (l + r < V) ob[(size_t)o * 4096 + l + r] = vv[r];
            }
        }
    }
}

extern "C" void kernel_launch(void* const* d_in, const int* in_sizes, int n_in,
                              void* d_out, int out_size, void* d_ws, size_t ws_size,
                              hipStream_t stream) {
    const float* x    = (const float*)d_in[0];
    const float* wgt  = (const float*)d_in[1];
    const float* bias = (const float*)d_in[2];
    float* out        = (float*)d_out;
    ushort* wt2       = (ushort*)d_ws;            // 4,718,592 B

    hipLaunchKernelGGL(wprep3_kernel, dim3(512), dim3(256), 0, stream, wgt, wt2);
    hipLaunchKernelGGL(conv5_kernel, dim3(1088), dim3(256), 0, stream, x, wt2, bias, out);
}